// Round 5
// baseline (454.452 us; speedup 1.0000x reference)
//
#include <hip/hip_runtime.h>
#include <stdint.h>

// Problem constants (fixed by the reference)
#define D_MODEL 1024
#define NHEADS  16
#define DEPTH   64
#define BATCH   2
#define SEQ     2048
#define M_TOT   (BATCH * SEQ)   // 4096

// 0.125 (1/sqrt(64)) * log2(e): folds softmax base-2 conversion into Q scale
#define Q_SCALE 0.18033688011112042f

typedef unsigned short u16;
typedef unsigned int   u32;
typedef __attribute__((ext_vector_type(8))) short bf16x8;  // 8 bf16 = 4 VGPRs
typedef __attribute__((ext_vector_type(4))) float f32x4;

__device__ __forceinline__ float bf2f(unsigned int u) {
    union { unsigned int i; float f; } x;
    x.i = (u & 0xffffu) << 16;
    return x.f;
}
__device__ __forceinline__ u16 f2bf(float f) {
    union { float f; unsigned int i; } x;
    x.f = f;
    unsigned int lsb = (x.i >> 16) & 1u;
    x.i += 0x7fffu + lsb;   // round-to-nearest-even
    return (u16)(x.i >> 16);
}
__device__ __forceinline__ u32 fbits(float f) {
    union { float f; unsigned int i; } x; x.f = f; return x.i;
}
// 2^x via v_exp_f32 (NOT __exp2f: that name collides with glibc's math.h)
__device__ __forceinline__ float exp2f_hw(float x) {
    return __builtin_amdgcn_exp2f(x);
}

// DPP cross-lane move within 16-lane rows (full-rate VALU, no LDS pipe)
template <int CTRL>
__device__ __forceinline__ float dppf(float x) {
    int r = __builtin_amdgcn_update_dpp(0, (int)fbits(x), CTRL, 0xF, 0xF, false);
    union { int i; float f; } u; u.i = r; return u.f;
}
// reduce across the 16 lanes of a DPP row (exact for sum: xor1,xor2,ror4,ror8)
__device__ __forceinline__ float redmax16(float x) {
    x = fmaxf(x, dppf<0xB1>(x));    // quad_perm(1,0,3,2) = xor1
    x = fmaxf(x, dppf<0x4E>(x));    // quad_perm(2,3,0,1) = xor2
    x = fmaxf(x, dppf<0x124>(x));   // row_ror:4
    x = fmaxf(x, dppf<0x128>(x));   // row_ror:8
    return x;
}
__device__ __forceinline__ float redsum16(float x) {
    x += dppf<0xB1>(x);
    x += dppf<0x4E>(x);
    x += dppf<0x124>(x);
    x += dppf<0x128>(x);
    return x;
}

// global -> LDS async 16B/lane; ldsbase wave-uniform, lane writes base+lane*16
__device__ __forceinline__ void stage16(const u16* g, u16* ldsbase) {
#if __has_builtin(__builtin_amdgcn_global_load_lds)
    __builtin_amdgcn_global_load_lds(
        (const __attribute__((address_space(1))) unsigned int*)g,
        (__attribute__((address_space(3))) unsigned int*)ldsbase, 16, 0, 0);
#else
    int lane = threadIdx.x & 63;
    *(uint4*)(ldsbase + lane * 8) = *(const uint4*)g;
#endif
}

// ---------------------------------------------------------------------------
// Dtype sniffer: flag=1 -> external tensors fp32, flag=0 -> bf16.
// ---------------------------------------------------------------------------
__global__ void sniff_kernel(const u16* __restrict__ q, int* __restrict__ flag) {
    const int t = threadIdx.x;  // one wave
    int cnt = 0;
    #pragma unroll
    for (int j = 0; j < 4; ++j) {
        unsigned int bits = q[2 * (t + 64 * j)];
        bool susp = ((bits & 0x7fffu) >= 0x4780u);
        cnt += (int)__popcll(__ballot(susp));
    }
    if (t == 0) flag[0] = (cnt >= 32) ? 1 : 0;
}

// ---------------------------------------------------------------------------
// Weight transpose (merged): W[K][N] -> WT[N][K] bf16, z selects the weight.
// ---------------------------------------------------------------------------
__global__ __launch_bounds__(256)
void wT_kernel(const void* W0, const void* W1, const void* W2, const void* W3,
               u16* T0, u16* T1, u16* T2, u16* T3, const int* __restrict__ flag) {
    __shared__ u16 t[64][72];
    const int z = blockIdx.z;
    const void* Wv = (z == 0) ? W0 : (z == 1) ? W1 : (z == 2) ? W2 : W3;
    u16* WT = (z == 0) ? T0 : (z == 1) ? T1 : (z == 2) ? T2 : T3;
    const int f32 = *flag;
    const int tid = threadIdx.x;
    const int n0 = blockIdx.x * 64, k0 = blockIdx.y * 64;

    #pragma unroll
    for (int cb = 0; cb < 2; ++cb) {
        int c = tid + cb * 256;
        int kl = c >> 3, nc = (c & 7) * 8;
        size_t off = (size_t)(k0 + kl) * D_MODEL + n0 + nc;
        u16 tmp[8];
        if (f32) {
            const float* W = (const float*)Wv;
            float4 a = *(const float4*)(W + off);
            float4 b = *(const float4*)(W + off + 4);
            tmp[0] = f2bf(a.x); tmp[1] = f2bf(a.y); tmp[2] = f2bf(a.z); tmp[3] = f2bf(a.w);
            tmp[4] = f2bf(b.x); tmp[5] = f2bf(b.y); tmp[6] = f2bf(b.z); tmp[7] = f2bf(b.w);
        } else {
            *(uint4*)tmp = *(const uint4*)((const u16*)Wv + off);
        }
        *(uint4*)&t[kl][nc] = *(uint4*)tmp;
    }
    __syncthreads();
    #pragma unroll
    for (int cb = 0; cb < 2; ++cb) {
        int c = tid + cb * 256;
        int nl = c >> 3, kc = (c & 7) * 8;
        u16 tmp[8];
        #pragma unroll
        for (int i = 0; i < 8; ++i) tmp[i] = t[kc + i][nl];
        *(uint4*)(WT + (size_t)(n0 + nl) * D_MODEL + k0 + kc) = *(uint4*)tmp;
    }
}

// ---------------------------------------------------------------------------
// m97-style GEMM: C[4096][1024] = A[4096][1024] @ BT^T + bias. BT is [N][K]
// bf16. 128x128 tile, BK=64, 4 waves (2x2), 16x16x32 bf16 MFMA, XOR-swizzled
// LDS (conflict-free frag reads), global_load_lds staging for bf16 operands,
// fp32->bf16 conversion folded into A staging when A is external fp32.
// cmode: 0 = bf16 ws row-major; 1 = permuted VpT' scatter; 2 = d_out.
// ---------------------------------------------------------------------------
struct GemmJob {
    const void* A;     // bf16 ws (a_ext=0) or external (dtype per flag)
    const u16*  BT;    // [N][K] bf16
    const void* bias;  // external dtype per flag
    void*       C;
    int a_ext;
    int cmode;
    float scale;
};

__global__ __launch_bounds__(256)
void gemm5(GemmJob j0, GemmJob j1, GemmJob j2, const int* __restrict__ flag) {
    __shared__ u16 Als[128 * 64];
    __shared__ u16 Bls[128 * 64];
    GemmJob jb = (blockIdx.z == 0) ? j0 : (blockIdx.z == 1) ? j1 : j2;

    const int f32 = *flag;
    const int af32 = jb.a_ext & f32;
    const int tid = threadIdx.x;
    const int w = tid >> 6, lane = tid & 63;
    const int cc = lane & 15, quad = lane >> 4;
    const int wm = w >> 1, wn = w & 1;
    const int m0 = blockIdx.y * 128, n0 = blockIdx.x * 128;

    f32x4 zero4 = {0.f, 0.f, 0.f, 0.f};
    f32x4 acc[4][4];
    #pragma unroll
    for (int i = 0; i < 4; ++i)
        #pragma unroll
        for (int j = 0; j < 4; ++j) acc[i][j] = zero4;

    // staging lane mapping (swizzled): lane's LDS col group is lane&7;
    // it fetches global group (lane&7)^(row&7) so LDS[row][g'] holds
    // global group g'^(row&7).
    const int srow_off = lane >> 3;           // row within 8-row chunk
    const int sg8 = ((lane & 7) ^ ((lane >> 3) & 7)) * 8;

    for (int k0 = 0; k0 < D_MODEL; k0 += 64) {
        __syncthreads();
        // B tile: rows n0..n0+127 of BT
        #pragma unroll
        for (int i = 0; i < 4; ++i) {
            int c = w * 4 + i;
            int row = c * 8 + srow_off;
            stage16(jb.BT + (size_t)(n0 + row) * D_MODEL + k0 + sg8, &Bls[c * 512]);
        }
        // A tile
        if (!af32) {
            const u16* A = (const u16*)jb.A;
            #pragma unroll
            for (int i = 0; i < 4; ++i) {
                int c = w * 4 + i;
                int row = c * 8 + srow_off;
                stage16(A + (size_t)(m0 + row) * D_MODEL + k0 + sg8, &Als[c * 512]);
            }
        } else {
            const float* A = (const float*)jb.A;
            #pragma unroll
            for (int c2 = 0; c2 < 4; ++c2) {
                int row = c2 * 32 + (tid >> 3);
                int gg = tid & 7;
                int lg = (gg ^ (row & 7)) * 8;
                const float* gp = A + (size_t)(m0 + row) * D_MODEL + k0 + gg * 8;
                float4 a = *(const float4*)gp;
                float4 b = *(const float4*)(gp + 4);
                u16 t8[8];
                t8[0] = f2bf(a.x); t8[1] = f2bf(a.y); t8[2] = f2bf(a.z); t8[3] = f2bf(a.w);
                t8[4] = f2bf(b.x); t8[5] = f2bf(b.y); t8[6] = f2bf(b.z); t8[7] = f2bf(b.w);
                *(uint4*)&Als[row * 64 + lg] = *(uint4*)t8;
            }
        }
        __syncthreads();

        // fragments: desired global k-group g = half*4+quad; LDS group = g^(cc&7)
        const int sw = cc & 7;
        bf16x8 af[4][2], bf[4][2];
        #pragma unroll
        for (int i = 0; i < 4; ++i) {
            const u16* ar = &Als[(wm * 64 + i * 16 + cc) * 64];
            af[i][0] = *(const bf16x8*)(ar + ((quad ^ sw) * 8));
            af[i][1] = *(const bf16x8*)(ar + (((4 + quad) ^ sw) * 8));
        }
        #pragma unroll
        for (int j = 0; j < 4; ++j) {
            const u16* br = &Bls[(wn * 64 + j * 16 + cc) * 64];
            bf[j][0] = *(const bf16x8*)(br + ((quad ^ sw) * 8));
            bf[j][1] = *(const bf16x8*)(br + (((4 + quad) ^ sw) * 8));
        }
        #pragma unroll
        for (int i = 0; i < 4; ++i)
            #pragma unroll
            for (int j = 0; j < 4; ++j) {
                acc[i][j] = __builtin_amdgcn_mfma_f32_16x16x32_bf16(af[i][0], bf[j][0], acc[i][j], 0, 0, 0);
                acc[i][j] = __builtin_amdgcn_mfma_f32_16x16x32_bf16(af[i][1], bf[j][1], acc[i][j], 0, 0, 0);
            }
    }

    // epilogue
    #pragma unroll
    for (int j = 0; j < 4; ++j) {
        int col = n0 + wn * 64 + j * 16 + cc;
        float bv = f32 ? ((const float*)jb.bias)[col] : bf2f(((const u16*)jb.bias)[col]);
        #pragma unroll
        for (int i = 0; i < 4; ++i)
            #pragma unroll
            for (int r = 0; r < 4; ++r) {
                int row = m0 + wm * 64 + i * 16 + quad * 4 + r;
                float vo = (acc[i][j][r] + bv) * jb.scale;
                if (jb.cmode == 0) {
                    ((u16*)jb.C)[(size_t)row * D_MODEL + col] = f2bf(vo);
                } else if (jb.cmode == 1) {
                    // permuted V^T scatter: VpT'[b][h][d][tile*64 + kappa],
                    // kappa = 4*(n&15) + (n>>4), n = token pos within 64-tile
                    int bb = row >> 11, tok = row & (SEQ - 1);
                    int hh = col >> 6, dd = col & 63;
                    int tile = tok >> 6, n = tok & 63;
                    int kap = ((n & 15) << 2) + (n >> 4);
                    ((u16*)jb.C)[((size_t)((bb * NHEADS + hh) * DEPTH + dd)) * SEQ
                                 + tile * 64 + kap] = f2bf(vo);
                } else {
                    if (f32) ((float*)jb.C)[(size_t)row * D_MODEL + col] = vo;
                    else     ((u16*)jb.C)[(size_t)row * D_MODEL + col] = f2bf(vo);
                }
            }
    }
}

// ---------------------------------------------------------------------------
// Barrier-free flash attention. Block = (qt rev-ordered, h, b), 4 waves;
// wave w owns 16 q-rows. K/V fragments loaded directly global->VGPR (no
// shared staging => no __syncthreads). P transposed C->A layout via
// wave-private LDS with permuted k (kappa = 4*cc+nb), matching VpT'.
// Softmax in exp2 domain (log2e folded into Q projection scale); DPP
// reductions; l-reduction deferred to epilogue.
// ---------------------------------------------------------------------------
__global__ __launch_bounds__(256, 4)
void attn2(const u16* __restrict__ Qp, const u16* __restrict__ Kp,
           const u16* __restrict__ VpT, u16* __restrict__ Ao) {
    __shared__ u16 Pls[4][16][72];

    const int tid = threadIdx.x;
    const int w = tid >> 6, lane = tid & 63;
    const int cc = lane & 15, quad = lane >> 4;
    const int qt = (int)(gridDim.x - 1 - blockIdx.x);   // descending for balance
    const int h = blockIdx.y, b = blockIdx.z;

    // Q A-frags (pre-scaled by Q_SCALE in the projection epilogue)
    bf16x8 qf0, qf1;
    {
        const u16* qr = Qp + (size_t)(b * SEQ + qt * 64 + w * 16 + cc) * D_MODEL + h * DEPTH;
        qf0 = *(const bf16x8*)(qr + quad * 8);
        qf1 = *(const bf16x8*)(qr + 32 + quad * 8);
    }

    f32x4 zero4 = {0.f, 0.f, 0.f, 0.f};
    f32x4 oacc[4] = {zero4, zero4, zero4, zero4};
    float m_run[4] = {-1e30f, -1e30f, -1e30f, -1e30f};
    float l_run[4] = {0.f, 0.f, 0.f, 0.f};

    const u16* kbase = Kp + (size_t)(b * SEQ) * D_MODEL + h * DEPTH;
    const u16* vbase = VpT + (size_t)((b * NHEADS + h) * DEPTH) * SEQ;

    for (int jt = 0; jt <= qt; ++jt) {
        // K B-frags direct from global: B[n=kpos][k=d]
        bf16x8 kf[4][2];
        #pragma unroll
        for (int nb = 0; nb < 4; ++nb) {
            const u16* kr = kbase + (size_t)(jt * 64 + nb * 16 + cc) * D_MODEL;
            kf[nb][0] = *(const bf16x8*)(kr + quad * 8);
            kf[nb][1] = *(const bf16x8*)(kr + 32 + quad * 8);
        }
        // S = Q K^T
        f32x4 s[4];
        #pragma unroll
        for (int nb = 0; nb < 4; ++nb) {
            s[nb] = __builtin_amdgcn_mfma_f32_16x16x32_bf16(qf0, kf[nb][0], zero4, 0, 0, 0);
            s[nb] = __builtin_amdgcn_mfma_f32_16x16x32_bf16(qf1, kf[nb][1], s[nb], 0, 0, 0);
        }
        if (jt == qt) {   // diagonal tile: causal mask (original kpos index n)
            #pragma unroll
            for (int nb = 0; nb < 4; ++nb)
                #pragma unroll
                for (int r = 0; r < 4; ++r)
                    if (nb * 16 + cc > w * 16 + quad * 4 + r) s[nb][r] = -1e30f;
        }

        // online softmax (base-2 domain)
        float mrow[4], alpha[4];
        #pragma unroll
        for (int r = 0; r < 4; ++r)
            mrow[r] = redmax16(fmaxf(fmaxf(s[0][r], s[1][r]), fmaxf(s[2][r], s[3][r])));
        #pragma unroll
        for (int r = 0; r < 4; ++r) {
            float mn = fmaxf(m_run[r], mrow[r]);
            alpha[r] = exp2f_hw(m_run[r] - mn);
            m_run[r] = mn;
        }
        #pragma unroll
        for (int nb = 0; nb < 4; ++nb)
            #pragma unroll
            for (int r = 0; r < 4; ++r)
                s[nb][r] = exp2f_hw(s[nb][r] - m_run[r]);
        #pragma unroll
        for (int r = 0; r < 4; ++r)
            l_run[r] = l_run[r] * alpha[r] + ((s[0][r] + s[1][r]) + (s[2][r] + s[3][r]));
        #pragma unroll
        for (int db = 0; db < 4; ++db)
            #pragma unroll
            for (int r = 0; r < 4; ++r)
                oacc[db][r] *= alpha[r];

        // P: C-layout -> A-layout, permuted k (kappa = 4*cc+nb), b64 writes,
        // bf16 truncation via v_perm (P in [0,1], <=0.4% rel err)
        #pragma unroll
        for (int r = 0; r < 4; ++r) {
            u32 p01 = __builtin_amdgcn_perm(fbits(s[1][r]), fbits(s[0][r]), 0x07060302u);
            u32 p23 = __builtin_amdgcn_perm(fbits(s[3][r]), fbits(s[2][r]), 0x07060302u);
            uint2 pk; pk.x = p01; pk.y = p23;
            *(uint2*)&Pls[w][quad * 4 + r][4 * cc] = pk;
        }
        __asm__ volatile("s_waitcnt lgkmcnt(0)" ::: "memory");
        bf16x8 pf0 = *(const bf16x8*)&Pls[w][cc][quad * 8];
        bf16x8 pf1 = *(const bf16x8*)&Pls[w][cc][32 + quad * 8];

        // V B-frags from permuted VpT': B[n=d][k=kappa]
        #pragma unroll
        for (int db = 0; db < 4; ++db) {
            const u16* vr = vbase + (size_t)(db * 16 + cc) * SEQ + jt * 64;
            bf16x8 v0 = *(const bf16x8*)(vr + quad * 8);
            bf16x8 v1 = *(const bf16x8*)(vr + 32 + quad * 8);
            oacc[db] = __builtin_amdgcn_mfma_f32_16x16x32_bf16(pf0, v0, oacc[db], 0, 0, 0);
            oacc[db] = __builtin_amdgcn_mfma_f32_16x16x32_bf16(pf1, v1, oacc[db], 0, 0, 0);
        }
    }

    // epilogue: reduce l across the 16 lanes, normalize, store
    float linv[4];
    #pragma unroll
    for (int r = 0; r < 4; ++r) linv[r] = 1.0f / redsum16(l_run[r]);
    #pragma unroll
    for (int db = 0; db < 4; ++db)
        #pragma unroll
        for (int r = 0; r < 4; ++r) {
            size_t row = (size_t)(b * SEQ + qt * 64 + w * 16 + quad * 4 + r);
            Ao[row * D_MODEL + h * DEPTH + db * 16 + cc] = f2bf(oacc[db][r] * linv[r]);
        }
}

// ---------------------------------------------------------------------------
extern "C" void kernel_launch(void* const* d_in, const int* in_sizes, int n_in,
                              void* d_out, int out_size, void* d_ws, size_t ws_size,
                              hipStream_t stream) {
    const void* v  = d_in[0];
    const void* k  = d_in[1];
    const void* q  = d_in[2];
    // d_in[3] = mask (unused: causal bound applied analytically)
    const void* Wq = d_in[4];
    const void* bq = d_in[5];
    const void* Wk = d_in[6];
    const void* bk = d_in[7];
    const void* Wv = d_in[8];
    const void* bv = d_in[9];
    const void* Wo = d_in[10];
    const void* bo = d_in[11];

    char* base = (char*)d_ws;
    int* flag = (int*)base;
    const size_t WSZ = (size_t)D_MODEL * D_MODEL;   // 1M elems (2MB bf16)
    const size_t TOK = (size_t)M_TOT * D_MODEL;     // 4M elems (8MB bf16)
    u16* WqT = (u16*)(base + 256);
    u16* WkT = WqT + WSZ;
    u16* WvT = WkT + WSZ;
    u16* WoT = WvT + WSZ;
    u16* Qp  = WoT + WSZ;
    u16* Kp  = Qp + TOK;
    u16* VpT = Kp + TOK;   // [B][H][DEPTH][SEQ], k-permuted per 64-tile
    u16* Ao  = VpT + TOK;  // total ~40.3 MB

    sniff_kernel<<<1, 64, 0, stream>>>((const u16*)q, flag);

    wT_kernel<<<dim3(16, 16, 4), 256, 0, stream>>>(Wq, Wk, Wv, Wo,
                                                   WqT, WkT, WvT, WoT, flag);

    GemmJob jq = {q,  WqT, bq, Qp,    1, 0, Q_SCALE};
    GemmJob jk = {k,  WkT, bk, Kp,    1, 0, 1.0f};
    GemmJob jv = {v,  WvT, bv, VpT,   1, 1, 1.0f};
    gemm5<<<dim3(8, 32, 3), 256, 0, stream>>>(jq, jk, jv, flag);

    attn2<<<dim3(32, 16, 2), 256, 0, stream>>>(Qp, Kp, VpT, Ao);

    GemmJob jo = {Ao, WoT, bo, d_out, 0, 2, 1.0f};
    gemm5<<<dim3(8, 32, 1), 256, 0, stream>>>(jo, jo, jo, flag);
}

// Round 6
// 303.837 us; speedup vs baseline: 1.4957x; 1.4957x over previous
//
#include <hip/hip_runtime.h>
#include <stdint.h>

// Problem constants (fixed by the reference)
#define D_MODEL 1024
#define NHEADS  16
#define DEPTH   64
#define BATCH   2
#define SEQ     2048
#define M_TOT   (BATCH * SEQ)   // 4096

// 0.125 (1/sqrt(64)) * log2(e): folds softmax base-2 conversion into Q scale
#define Q_SCALE 0.18033688011112042f

typedef unsigned short u16;
typedef unsigned int   u32;
typedef __attribute__((ext_vector_type(8))) short bf16x8;  // 8 bf16 = 4 VGPRs
typedef __attribute__((ext_vector_type(4))) float f32x4;

__device__ __forceinline__ float bf2f(unsigned int u) {
    union { unsigned int i; float f; } x;
    x.i = (u & 0xffffu) << 16;
    return x.f;
}
__device__ __forceinline__ u16 f2bf(float f) {
    union { float f; unsigned int i; } x;
    x.f = f;
    unsigned int lsb = (x.i >> 16) & 1u;
    x.i += 0x7fffu + lsb;   // round-to-nearest-even
    return (u16)(x.i >> 16);
}
__device__ __forceinline__ u32 fbits(float f) {
    union { float f; unsigned int i; } x; x.f = f; return x.i;
}
// 2^x via v_exp_f32 (NOT __exp2f: that name collides with glibc's math.h)
__device__ __forceinline__ float exp2f_hw(float x) {
    return __builtin_amdgcn_exp2f(x);
}

// DPP cross-lane move within 16-lane rows (full-rate VALU, no LDS pipe)
template <int CTRL>
__device__ __forceinline__ float dppf(float x) {
    int r = __builtin_amdgcn_update_dpp(0, (int)fbits(x), CTRL, 0xF, 0xF, false);
    union { int i; float f; } u; u.i = r; return u.f;
}
__device__ __forceinline__ float redmax16(float x) {
    x = fmaxf(x, dppf<0xB1>(x));    // xor1
    x = fmaxf(x, dppf<0x4E>(x));    // xor2
    x = fmaxf(x, dppf<0x124>(x));   // row_ror:4
    x = fmaxf(x, dppf<0x128>(x));   // row_ror:8
    return x;
}
__device__ __forceinline__ float redsum16(float x) {
    x += dppf<0xB1>(x);
    x += dppf<0x4E>(x);
    x += dppf<0x124>(x);
    x += dppf<0x128>(x);
    return x;
}

// global -> LDS async 16B/lane; ldsbase wave-uniform, lane writes base+lane*16
__device__ __forceinline__ void stage16(const u16* g, u16* ldsbase) {
#if __has_builtin(__builtin_amdgcn_global_load_lds)
    __builtin_amdgcn_global_load_lds(
        (const __attribute__((address_space(1))) unsigned int*)g,
        (__attribute__((address_space(3))) unsigned int*)ldsbase, 16, 0, 0);
#else
    int lane = threadIdx.x & 63;
    *(uint4*)(ldsbase + lane * 8) = *(const uint4*)g;
#endif
}

// ---------------------------------------------------------------------------
// Dtype sniffer: flag=1 -> external tensors fp32, flag=0 -> bf16.
// ---------------------------------------------------------------------------
__global__ void sniff_kernel(const u16* __restrict__ q, int* __restrict__ flag) {
    const int t = threadIdx.x;  // one wave
    int cnt = 0;
    #pragma unroll
    for (int j = 0; j < 4; ++j) {
        unsigned int bits = q[2 * (t + 64 * j)];
        bool susp = ((bits & 0x7fffu) >= 0x4780u);
        cnt += (int)__popcll(__ballot(susp));
    }
    if (t == 0) flag[0] = (cnt >= 32) ? 1 : 0;
}

// ---------------------------------------------------------------------------
// Weight transpose (merged): W[K][N] -> WT[N][K] bf16, z selects the weight.
// ---------------------------------------------------------------------------
__global__ __launch_bounds__(256)
void wT_kernel(const void* W0, const void* W1, const void* W2, const void* W3,
               u16* T0, u16* T1, u16* T2, u16* T3, const int* __restrict__ flag) {
    __shared__ u16 t[64][72];
    const int z = blockIdx.z;
    const void* Wv = (z == 0) ? W0 : (z == 1) ? W1 : (z == 2) ? W2 : W3;
    u16* WT = (z == 0) ? T0 : (z == 1) ? T1 : (z == 2) ? T2 : T3;
    const int f32 = *flag;
    const int tid = threadIdx.x;
    const int n0 = blockIdx.x * 64, k0 = blockIdx.y * 64;

    #pragma unroll
    for (int cb = 0; cb < 2; ++cb) {
        int c = tid + cb * 256;
        int kl = c >> 3, nc = (c & 7) * 8;
        size_t off = (size_t)(k0 + kl) * D_MODEL + n0 + nc;
        u16 tmp[8];
        if (f32) {
            const float* W = (const float*)Wv;
            float4 a = *(const float4*)(W + off);
            float4 b = *(const float4*)(W + off + 4);
            tmp[0] = f2bf(a.x); tmp[1] = f2bf(a.y); tmp[2] = f2bf(a.z); tmp[3] = f2bf(a.w);
            tmp[4] = f2bf(b.x); tmp[5] = f2bf(b.y); tmp[6] = f2bf(b.z); tmp[7] = f2bf(b.w);
        } else {
            *(uint4*)tmp = *(const uint4*)((const u16*)Wv + off);
        }
        *(uint4*)&t[kl][nc] = *(uint4*)tmp;
    }
    __syncthreads();
    #pragma unroll
    for (int cb = 0; cb < 2; ++cb) {
        int c = tid + cb * 256;
        int nl = c >> 3, kc = (c & 7) * 8;
        u16 tmp[8];
        #pragma unroll
        for (int i = 0; i < 8; ++i) tmp[i] = t[kc + i][nl];
        *(uint4*)(WT + (size_t)(n0 + nl) * D_MODEL + k0 + kc) = *(uint4*)tmp;
    }
}

// ---------------------------------------------------------------------------
// m97-style GEMM (unchanged from round 5 — validated).
// ---------------------------------------------------------------------------
struct GemmJob {
    const void* A;
    const u16*  BT;    // [N][K] bf16
    const void* bias;
    void*       C;
    int a_ext;
    int cmode;
    float scale;
};

__global__ __launch_bounds__(256)
void gemm5(GemmJob j0, GemmJob j1, GemmJob j2, const int* __restrict__ flag) {
    __shared__ u16 Als[128 * 64];
    __shared__ u16 Bls[128 * 64];
    GemmJob jb = (blockIdx.z == 0) ? j0 : (blockIdx.z == 1) ? j1 : j2;

    const int f32 = *flag;
    const int af32 = jb.a_ext & f32;
    const int tid = threadIdx.x;
    const int w = tid >> 6, lane = tid & 63;
    const int cc = lane & 15, quad = lane >> 4;
    const int wm = w >> 1, wn = w & 1;
    const int m0 = blockIdx.y * 128, n0 = blockIdx.x * 128;

    f32x4 zero4 = {0.f, 0.f, 0.f, 0.f};
    f32x4 acc[4][4];
    #pragma unroll
    for (int i = 0; i < 4; ++i)
        #pragma unroll
        for (int j = 0; j < 4; ++j) acc[i][j] = zero4;

    const int srow_off = lane >> 3;
    const int sg8 = ((lane & 7) ^ ((lane >> 3) & 7)) * 8;

    for (int k0 = 0; k0 < D_MODEL; k0 += 64) {
        __syncthreads();
        #pragma unroll
        for (int i = 0; i < 4; ++i) {
            int c = w * 4 + i;
            int row = c * 8 + srow_off;
            stage16(jb.BT + (size_t)(n0 + row) * D_MODEL + k0 + sg8, &Bls[c * 512]);
        }
        if (!af32) {
            const u16* A = (const u16*)jb.A;
            #pragma unroll
            for (int i = 0; i < 4; ++i) {
                int c = w * 4 + i;
                int row = c * 8 + srow_off;
                stage16(A + (size_t)(m0 + row) * D_MODEL + k0 + sg8, &Als[c * 512]);
            }
        } else {
            const float* A = (const float*)jb.A;
            #pragma unroll
            for (int c2 = 0; c2 < 4; ++c2) {
                int row = c2 * 32 + (tid >> 3);
                int gg = tid & 7;
                int lg = (gg ^ (row & 7)) * 8;
                const float* gp = A + (size_t)(m0 + row) * D_MODEL + k0 + gg * 8;
                float4 a = *(const float4*)gp;
                float4 b = *(const float4*)(gp + 4);
                u16 t8[8];
                t8[0] = f2bf(a.x); t8[1] = f2bf(a.y); t8[2] = f2bf(a.z); t8[3] = f2bf(a.w);
                t8[4] = f2bf(b.x); t8[5] = f2bf(b.y); t8[6] = f2bf(b.z); t8[7] = f2bf(b.w);
                *(uint4*)&Als[row * 64 + lg] = *(uint4*)t8;
            }
        }
        __syncthreads();

        const int sw = cc & 7;
        bf16x8 af[4][2], bf[4][2];
        #pragma unroll
        for (int i = 0; i < 4; ++i) {
            const u16* ar = &Als[(wm * 64 + i * 16 + cc) * 64];
            af[i][0] = *(const bf16x8*)(ar + ((quad ^ sw) * 8));
            af[i][1] = *(const bf16x8*)(ar + (((4 + quad) ^ sw) * 8));
        }
        #pragma unroll
        for (int j = 0; j < 4; ++j) {
            const u16* br = &Bls[(wn * 64 + j * 16 + cc) * 64];
            bf[j][0] = *(const bf16x8*)(br + ((quad ^ sw) * 8));
            bf[j][1] = *(const bf16x8*)(br + (((4 + quad) ^ sw) * 8));
        }
        #pragma unroll
        for (int i = 0; i < 4; ++i)
            #pragma unroll
            for (int j = 0; j < 4; ++j) {
                acc[i][j] = __builtin_amdgcn_mfma_f32_16x16x32_bf16(af[i][0], bf[j][0], acc[i][j], 0, 0, 0);
                acc[i][j] = __builtin_amdgcn_mfma_f32_16x16x32_bf16(af[i][1], bf[j][1], acc[i][j], 0, 0, 0);
            }
    }

    #pragma unroll
    for (int j = 0; j < 4; ++j) {
        int col = n0 + wn * 64 + j * 16 + cc;
        float bv = f32 ? ((const float*)jb.bias)[col] : bf2f(((const u16*)jb.bias)[col]);
        #pragma unroll
        for (int i = 0; i < 4; ++i)
            #pragma unroll
            for (int r = 0; r < 4; ++r) {
                int row = m0 + wm * 64 + i * 16 + quad * 4 + r;
                float vo = (acc[i][j][r] + bv) * jb.scale;
                if (jb.cmode == 0) {
                    ((u16*)jb.C)[(size_t)row * D_MODEL + col] = f2bf(vo);
                } else if (jb.cmode == 1) {
                    int bb = row >> 11, tok = row & (SEQ - 1);
                    int hh = col >> 6, dd = col & 63;
                    int tile = tok >> 6, n = tok & 63;
                    int kap = ((n & 15) << 2) + (n >> 4);
                    ((u16*)jb.C)[((size_t)((bb * NHEADS + hh) * DEPTH + dd)) * SEQ
                                 + tile * 64 + kap] = f2bf(vo);
                } else {
                    if (f32) ((float*)jb.C)[(size_t)row * D_MODEL + col] = vo;
                    else     ((u16*)jb.C)[(size_t)row * D_MODEL + col] = f2bf(vo);
                }
            }
    }
}

// ---------------------------------------------------------------------------
// Pipelined cooperative flash attention. Block = 128 Q-rows x (h, b); 4
// waves, wave w owns rows w*32..w*32+31 (2 m-frags). K/V tiles of 64 staged
// cooperatively via global_load_lds (XOR-swizzled, double-buffered); ONE
// barrier per K-tile; prefetch of jt+1 overlaps compute of jt. P transpose
// via wave-private LDS (kappa-permuted, matching VpT'); compiler-only fence
// (DS pipe is in-order per wave). Softmax exp2-domain with DPP reductions.
// ---------------------------------------------------------------------------
__global__ __launch_bounds__(256, 3)
void attn3(const u16* __restrict__ Qp, const u16* __restrict__ Kp,
           const u16* __restrict__ VpT, u16* __restrict__ Ao) {
    __shared__ u16 Kls[2][64 * 64];
    __shared__ u16 Vls[2][64 * 64];
    __shared__ u16 Pls[4][32][72];

    const int tid = threadIdx.x;
    const int w = tid >> 6, lane = tid & 63;
    const int cc = lane & 15, quad = lane >> 4;
    const int qt = (int)(gridDim.x - 1 - blockIdx.x);   // descending for balance
    const int h = blockIdx.y, b = blockIdx.z;
    const int qbase = qt * 128 + w * 32;                // wave's first q row

    // Q A-frags (pre-scaled by Q_SCALE in the projection epilogue)
    bf16x8 qf[2][2];
    #pragma unroll
    for (int mi = 0; mi < 2; ++mi) {
        const u16* qr = Qp + (size_t)(b * SEQ + qbase + mi * 16 + cc) * D_MODEL + h * DEPTH;
        qf[mi][0] = *(const bf16x8*)(qr + quad * 8);
        qf[mi][1] = *(const bf16x8*)(qr + 32 + quad * 8);
    }

    const u16* kbase = Kp + (size_t)(b * SEQ) * D_MODEL + h * DEPTH;
    const u16* vbase = VpT + (size_t)((b * NHEADS + h) * DEPTH) * SEQ;

    // staging lane mapping (XOR-swizzled, same scheme as gemm5)
    const int r8 = lane >> 3;
    const int g8 = ((lane & 7) ^ (r8 & 7)) * 8;

    auto stageKV = [&](int buf, int jt) {
        #pragma unroll
        for (int i = 0; i < 2; ++i) {
            int row = w * 16 + i * 8 + r8;   // local row 0..63
            stage16(kbase + (size_t)(jt * 64 + row) * D_MODEL + g8,
                    &Kls[buf][(w * 16 + i * 8) * 64]);
            stage16(vbase + (size_t)row * SEQ + jt * 64 + g8,
                    &Vls[buf][(w * 16 + i * 8) * 64]);
        }
    };

    f32x4 zero4 = {0.f, 0.f, 0.f, 0.f};
    f32x4 oacc[2][4];
    #pragma unroll
    for (int mi = 0; mi < 2; ++mi)
        #pragma unroll
        for (int db = 0; db < 4; ++db) oacc[mi][db] = zero4;
    float m_run[2][4], l_run[2][4];
    #pragma unroll
    for (int mi = 0; mi < 2; ++mi)
        #pragma unroll
        for (int r = 0; r < 4; ++r) { m_run[mi][r] = -1e30f; l_run[mi][r] = 0.f; }

    const int jtmax = 2 * qt + 1;
    stageKV(0, 0);

    for (int jt = 0; jt <= jtmax; ++jt) {
        const int cur = jt & 1;
        __syncthreads();                      // drains DMA for buf cur, syncs waves
        if (jt < jtmax) stageKV(cur ^ 1, jt + 1);   // async prefetch overlaps compute

        if (jt * 64 > qbase + 31) continue;   // tile fully masked for this wave

        const int sw = cc & 7;
        // K B-frags from LDS (swizzled)
        bf16x8 kf[4][2];
        #pragma unroll
        for (int nb = 0; nb < 4; ++nb) {
            const u16* kr = &Kls[cur][(nb * 16 + cc) * 64];
            kf[nb][0] = *(const bf16x8*)(kr + ((quad ^ sw) * 8));
            kf[nb][1] = *(const bf16x8*)(kr + (((4 + quad) ^ sw) * 8));
        }
        // S = Q K^T
        f32x4 s[2][4];
        #pragma unroll
        for (int mi = 0; mi < 2; ++mi)
            #pragma unroll
            for (int nb = 0; nb < 4; ++nb) {
                s[mi][nb] = __builtin_amdgcn_mfma_f32_16x16x32_bf16(qf[mi][0], kf[nb][0], zero4, 0, 0, 0);
                s[mi][nb] = __builtin_amdgcn_mfma_f32_16x16x32_bf16(qf[mi][1], kf[nb][1], s[mi][nb], 0, 0, 0);
            }
        // causal mask (only on tiles that touch the diagonal of this wave)
        #pragma unroll
        for (int mi = 0; mi < 2; ++mi) {
            if (jt * 64 + 63 > qbase + mi * 16) {
                #pragma unroll
                for (int nb = 0; nb < 4; ++nb)
                    #pragma unroll
                    for (int r = 0; r < 4; ++r)
                        if (jt * 64 + nb * 16 + cc > qbase + mi * 16 + quad * 4 + r)
                            s[mi][nb][r] = -1e30f;
            }
        }

        // online softmax (base-2 domain), per mi
        float alpha[2][4];
        #pragma unroll
        for (int mi = 0; mi < 2; ++mi) {
            #pragma unroll
            for (int r = 0; r < 4; ++r) {
                float mrow = redmax16(fmaxf(fmaxf(s[mi][0][r], s[mi][1][r]),
                                            fmaxf(s[mi][2][r], s[mi][3][r])));
                float mn = fmaxf(m_run[mi][r], mrow);
                alpha[mi][r] = exp2f_hw(m_run[mi][r] - mn);
                m_run[mi][r] = mn;
            }
            #pragma unroll
            for (int nb = 0; nb < 4; ++nb)
                #pragma unroll
                for (int r = 0; r < 4; ++r)
                    s[mi][nb][r] = exp2f_hw(s[mi][nb][r] - m_run[mi][r]);
            #pragma unroll
            for (int r = 0; r < 4; ++r)
                l_run[mi][r] = l_run[mi][r] * alpha[mi][r]
                             + ((s[mi][0][r] + s[mi][1][r]) + (s[mi][2][r] + s[mi][3][r]));
            #pragma unroll
            for (int db = 0; db < 4; ++db)
                #pragma unroll
                for (int r = 0; r < 4; ++r)
                    oacc[mi][db][r] *= alpha[mi][r];
        }

        // P: C-layout -> A-layout, kappa = 4*cc+nb (matches VpT'), b64 writes
        #pragma unroll
        for (int mi = 0; mi < 2; ++mi)
            #pragma unroll
            for (int r = 0; r < 4; ++r) {
                u32 p01 = __builtin_amdgcn_perm(fbits(s[mi][1][r]), fbits(s[mi][0][r]), 0x07060302u);
                u32 p23 = __builtin_amdgcn_perm(fbits(s[mi][3][r]), fbits(s[mi][2][r]), 0x07060302u);
                uint2 pk; pk.x = p01; pk.y = p23;
                *(uint2*)&Pls[w][mi * 16 + quad * 4 + r][4 * cc] = pk;
            }
        // compiler-only fence: DS pipe is in-order per wave; just prevent
        // the compiler from reordering the ds_reads above the ds_writes.
        __asm__ volatile("" ::: "memory");

        bf16x8 pf[2][2];
        #pragma unroll
        for (int mi = 0; mi < 2; ++mi) {
            pf[mi][0] = *(const bf16x8*)&Pls[w][mi * 16 + cc][quad * 8];
            pf[mi][1] = *(const bf16x8*)&Pls[w][mi * 16 + cc][32 + quad * 8];
        }
        // V B-frags from LDS (swizzled); O += P V
        #pragma unroll
        for (int db = 0; db < 4; ++db) {
            const u16* vr = &Vls[cur][(db * 16 + cc) * 64];
            bf16x8 v0 = *(const bf16x8*)(vr + ((quad ^ sw) * 8));
            bf16x8 v1 = *(const bf16x8*)(vr + (((4 + quad) ^ sw) * 8));
            #pragma unroll
            for (int mi = 0; mi < 2; ++mi) {
                oacc[mi][db] = __builtin_amdgcn_mfma_f32_16x16x32_bf16(pf[mi][0], v0, oacc[mi][db], 0, 0, 0);
                oacc[mi][db] = __builtin_amdgcn_mfma_f32_16x16x32_bf16(pf[mi][1], v1, oacc[mi][db], 0, 0, 0);
            }
        }
    }

    // epilogue: reduce l across the 16 lanes, normalize, store
    #pragma unroll
    for (int mi = 0; mi < 2; ++mi) {
        float linv[4];
        #pragma unroll
        for (int r = 0; r < 4; ++r) linv[r] = 1.0f / redsum16(l_run[mi][r]);
        #pragma unroll
        for (int db = 0; db < 4; ++db)
            #pragma unroll
            for (int r = 0; r < 4; ++r) {
                size_t row = (size_t)(b * SEQ + qbase + mi * 16 + quad * 4 + r);
                Ao[row * D_MODEL + h * DEPTH + db * 16 + cc] =
                    f2bf(oacc[mi][db][r] * linv[r]);
            }
    }
}

// ---------------------------------------------------------------------------
extern "C" void kernel_launch(void* const* d_in, const int* in_sizes, int n_in,
                              void* d_out, int out_size, void* d_ws, size_t ws_size,
                              hipStream_t stream) {
    const void* v  = d_in[0];
    const void* k  = d_in[1];
    const void* q  = d_in[2];
    // d_in[3] = mask (unused: causal bound applied analytically)
    const void* Wq = d_in[4];
    const void* bq = d_in[5];
    const void* Wk = d_in[6];
    const void* bk = d_in[7];
    const void* Wv = d_in[8];
    const void* bv = d_in[9];
    const void* Wo = d_in[10];
    const void* bo = d_in[11];

    char* base = (char*)d_ws;
    int* flag = (int*)base;
    const size_t WSZ = (size_t)D_MODEL * D_MODEL;   // 1M elems (2MB bf16)
    const size_t TOK = (size_t)M_TOT * D_MODEL;     // 4M elems (8MB bf16)
    u16* WqT = (u16*)(base + 256);
    u16* WkT = WqT + WSZ;
    u16* WvT = WkT + WSZ;
    u16* WoT = WvT + WSZ;
    u16* Qp  = WoT + WSZ;
    u16* Kp  = Qp + TOK;
    u16* VpT = Kp + TOK;   // [B][H][DEPTH][SEQ], kappa-permuted per 64-tile
    u16* Ao  = VpT + TOK;  // total ~40.3 MB

    sniff_kernel<<<1, 64, 0, stream>>>((const u16*)q, flag);

    wT_kernel<<<dim3(16, 16, 4), 256, 0, stream>>>(Wq, Wk, Wv, Wo,
                                                   WqT, WkT, WvT, WoT, flag);

    GemmJob jq = {q,  WqT, bq, Qp,    1, 0, Q_SCALE};
    GemmJob jk = {k,  WkT, bk, Kp,    1, 0, 1.0f};
    GemmJob jv = {v,  WvT, bv, VpT,   1, 1, 1.0f};
    gemm5<<<dim3(8, 32, 3), 256, 0, stream>>>(jq, jk, jv, flag);

    attn3<<<dim3(16, 16, 2), 256, 0, stream>>>(Qp, Kp, VpT, Ao);

    GemmJob jo = {Ao, WoT, bo, d_out, 0, 2, 1.0f};
    gemm5<<<dim3(8, 32, 1), 256, 0, stream>>>(jo, jo, jo, flag);
}

// Round 7
// 299.492 us; speedup vs baseline: 1.5174x; 1.0145x over previous
//
#include <hip/hip_runtime.h>
#include <stdint.h>

// Problem constants (fixed by the reference)
#define D_MODEL 1024
#define NHEADS  16
#define DEPTH   64
#define BATCH   2
#define SEQ     2048
#define M_TOT   (BATCH * SEQ)   // 4096

// 0.125 (1/sqrt(64)) * log2(e): folds softmax base-2 conversion into Q scale
#define Q_SCALE 0.18033688011112042f

typedef unsigned short u16;
typedef unsigned int   u32;
typedef __attribute__((ext_vector_type(8))) short bf16x8;  // 8 bf16 = 4 VGPRs
typedef __attribute__((ext_vector_type(4))) float f32x4;

__device__ __forceinline__ float bf2f(unsigned int u) {
    union { unsigned int i; float f; } x;
    x.i = (u & 0xffffu) << 16;
    return x.f;
}
__device__ __forceinline__ u16 f2bf(float f) {
    union { float f; unsigned int i; } x;
    x.f = f;
    unsigned int lsb = (x.i >> 16) & 1u;
    x.i += 0x7fffu + lsb;   // round-to-nearest-even
    return (u16)(x.i >> 16);
}
__device__ __forceinline__ u32 fbits(float f) {
    union { float f; unsigned int i; } x; x.f = f; return x.i;
}
// 2^x via v_exp_f32 (NOT __exp2f: that name collides with glibc's math.h)
__device__ __forceinline__ float exp2f_hw(float x) {
    return __builtin_amdgcn_exp2f(x);
}

// DPP cross-lane move within 16-lane rows (full-rate VALU, no LDS pipe)
template <int CTRL>
__device__ __forceinline__ float dppf(float x) {
    int r = __builtin_amdgcn_update_dpp(0, (int)fbits(x), CTRL, 0xF, 0xF, false);
    union { int i; float f; } u; u.i = r; return u.f;
}
__device__ __forceinline__ float redmax16(float x) {
    x = fmaxf(x, dppf<0xB1>(x));    // xor1
    x = fmaxf(x, dppf<0x4E>(x));    // xor2
    x = fmaxf(x, dppf<0x124>(x));   // row_ror:4
    x = fmaxf(x, dppf<0x128>(x));   // row_ror:8
    return x;
}
__device__ __forceinline__ float redsum16(float x) {
    x += dppf<0xB1>(x);
    x += dppf<0x4E>(x);
    x += dppf<0x124>(x);
    x += dppf<0x128>(x);
    return x;
}

// global -> LDS async 16B/lane; ldsbase wave-uniform, lane writes base+lane*16
__device__ __forceinline__ void stage16(const u16* g, u16* ldsbase) {
#if __has_builtin(__builtin_amdgcn_global_load_lds)
    __builtin_amdgcn_global_load_lds(
        (const __attribute__((address_space(1))) unsigned int*)g,
        (__attribute__((address_space(3))) unsigned int*)ldsbase, 16, 0, 0);
#else
    int lane = threadIdx.x & 63;
    *(uint4*)(ldsbase + lane * 8) = *(const uint4*)g;
#endif
}

// ---------------------------------------------------------------------------
// Dtype sniffer: flag=1 -> external tensors fp32, flag=0 -> bf16.
// ---------------------------------------------------------------------------
__global__ void sniff_kernel(const u16* __restrict__ q, int* __restrict__ flag) {
    const int t = threadIdx.x;  // one wave
    int cnt = 0;
    #pragma unroll
    for (int j = 0; j < 4; ++j) {
        unsigned int bits = q[2 * (t + 64 * j)];
        bool susp = ((bits & 0x7fffu) >= 0x4780u);
        cnt += (int)__popcll(__ballot(susp));
    }
    if (t == 0) flag[0] = (cnt >= 32) ? 1 : 0;
}

// ---------------------------------------------------------------------------
// Input conversion: q/k/v (fp32 or bf16 per flag) -> contiguous bf16.
// Streaming, 8 elements/thread/iter; memory-bound (~72 MB total).
// ---------------------------------------------------------------------------
__global__ __launch_bounds__(256)
void conv_kernel(const void* s0, const void* s1, const void* s2,
                 u16* d0, u16* d1, u16* d2, const int* __restrict__ flag) {
    const int z = blockIdx.z;
    const void* src = (z == 0) ? s0 : (z == 1) ? s1 : s2;
    u16* dst = (z == 0) ? d0 : (z == 1) ? d1 : d2;
    const int f32 = *flag;
    const size_t i = ((size_t)blockIdx.x * 256 + threadIdx.x) * 8;
    if (f32) {
        const float* s = (const float*)src + i;
        float4 a = *(const float4*)s;
        float4 b = *(const float4*)(s + 4);
        u16 t8[8];
        t8[0] = f2bf(a.x); t8[1] = f2bf(a.y); t8[2] = f2bf(a.z); t8[3] = f2bf(a.w);
        t8[4] = f2bf(b.x); t8[5] = f2bf(b.y); t8[6] = f2bf(b.z); t8[7] = f2bf(b.w);
        *(uint4*)(dst + i) = *(uint4*)t8;
    } else {
        *(uint4*)(dst + i) = *(const uint4*)((const u16*)src + i);
    }
}

// ---------------------------------------------------------------------------
// Weight transpose (merged): W[K][N] -> WT[N][K] bf16, z selects the weight.
// ---------------------------------------------------------------------------
__global__ __launch_bounds__(256)
void wT_kernel(const void* W0, const void* W1, const void* W2, const void* W3,
               u16* T0, u16* T1, u16* T2, u16* T3, const int* __restrict__ flag) {
    __shared__ u16 t[64][72];
    const int z = blockIdx.z;
    const void* Wv = (z == 0) ? W0 : (z == 1) ? W1 : (z == 2) ? W2 : W3;
    u16* WT = (z == 0) ? T0 : (z == 1) ? T1 : (z == 2) ? T2 : T3;
    const int f32 = *flag;
    const int tid = threadIdx.x;
    const int n0 = blockIdx.x * 64, k0 = blockIdx.y * 64;

    #pragma unroll
    for (int cb = 0; cb < 2; ++cb) {
        int c = tid + cb * 256;
        int kl = c >> 3, nc = (c & 7) * 8;
        size_t off = (size_t)(k0 + kl) * D_MODEL + n0 + nc;
        u16 tmp[8];
        if (f32) {
            const float* W = (const float*)Wv;
            float4 a = *(const float4*)(W + off);
            float4 b = *(const float4*)(W + off + 4);
            tmp[0] = f2bf(a.x); tmp[1] = f2bf(a.y); tmp[2] = f2bf(a.z); tmp[3] = f2bf(a.w);
            tmp[4] = f2bf(b.x); tmp[5] = f2bf(b.y); tmp[6] = f2bf(b.z); tmp[7] = f2bf(b.w);
        } else {
            *(uint4*)tmp = *(const uint4*)((const u16*)Wv + off);
        }
        *(uint4*)&t[kl][nc] = *(uint4*)tmp;
    }
    __syncthreads();
    #pragma unroll
    for (int cb = 0; cb < 2; ++cb) {
        int c = tid + cb * 256;
        int nl = c >> 3, kc = (c & 7) * 8;
        u16 tmp[8];
        #pragma unroll
        for (int i = 0; i < 8; ++i) tmp[i] = t[kc + i][nl];
        *(uint4*)(WT + (size_t)(n0 + nl) * D_MODEL + k0 + kc) = *(uint4*)tmp;
    }
}

// ---------------------------------------------------------------------------
// m97-style GEMM, all-bf16 operands, XCD-aware swizzle. C = A @ BT^T + bias.
// 128x128 tile, BK=64, 4 waves (2x2), 16x16x32 bf16 MFMA, XOR-swizzled LDS,
// global_load_lds staging for BOTH operands.
// Swizzle: gridDim.x must be 8. lin -> xcd = lin&7 owns whole (m,z) groups,
// so all 8 n-tiles sharing an A-stripe land on ONE XCD (A fetched once/L2).
// cmode: 0 = bf16 ws row-major; 1 = kappa-permuted VpT' scatter; 2 = d_out.
// ---------------------------------------------------------------------------
struct GemmJob {
    const u16*  A;     // bf16 ws [4096][1024]
    const u16*  BT;    // [N][K] bf16
    const void* bias;  // external dtype per flag
    void*       C;
    int cmode;
    float scale;
};

__global__ __launch_bounds__(256)
void gemm6(GemmJob j0, GemmJob j1, GemmJob j2, const int* __restrict__ flag) {
    __shared__ u16 Als[128 * 64];
    __shared__ u16 Bls[128 * 64];

    // XCD-aware swizzle (gridDim.x == 8)
    const u32 lin = blockIdx.x + gridDim.x * (blockIdx.y + gridDim.y * blockIdx.z);
    const u32 xcd = lin & 7, idx = lin >> 3;
    const u32 per = (gridDim.y * gridDim.z) >> 3;   // (m,z) groups per XCD
    const u32 mz = xcd * per + (idx >> 3);
    const u32 nb_ = idx & 7;
    const u32 zz = mz / gridDim.y;
    const u32 my = mz % gridDim.y;
    GemmJob jb = (zz == 0) ? j0 : (zz == 1) ? j1 : j2;

    const int f32 = *flag;
    const int tid = threadIdx.x;
    const int w = tid >> 6, lane = tid & 63;
    const int cc = lane & 15, quad = lane >> 4;
    const int wm = w >> 1, wn = w & 1;
    const int m0 = my * 128, n0 = nb_ * 128;

    f32x4 zero4 = {0.f, 0.f, 0.f, 0.f};
    f32x4 acc[4][4];
    #pragma unroll
    for (int i = 0; i < 4; ++i)
        #pragma unroll
        for (int j = 0; j < 4; ++j) acc[i][j] = zero4;

    const int srow_off = lane >> 3;
    const int sg8 = ((lane & 7) ^ ((lane >> 3) & 7)) * 8;

    for (int k0 = 0; k0 < D_MODEL; k0 += 64) {
        __syncthreads();
        #pragma unroll
        for (int i = 0; i < 4; ++i) {
            int c = w * 4 + i;
            int row = c * 8 + srow_off;
            stage16(jb.BT + (size_t)(n0 + row) * D_MODEL + k0 + sg8, &Bls[c * 512]);
            stage16(jb.A  + (size_t)(m0 + row) * D_MODEL + k0 + sg8, &Als[c * 512]);
        }
        __syncthreads();

        const int sw = cc & 7;
        bf16x8 af[4][2], bf[4][2];
        #pragma unroll
        for (int i = 0; i < 4; ++i) {
            const u16* ar = &Als[(wm * 64 + i * 16 + cc) * 64];
            af[i][0] = *(const bf16x8*)(ar + ((quad ^ sw) * 8));
            af[i][1] = *(const bf16x8*)(ar + (((4 + quad) ^ sw) * 8));
        }
        #pragma unroll
        for (int j = 0; j < 4; ++j) {
            const u16* br = &Bls[(wn * 64 + j * 16 + cc) * 64];
            bf[j][0] = *(const bf16x8*)(br + ((quad ^ sw) * 8));
            bf[j][1] = *(const bf16x8*)(br + (((4 + quad) ^ sw) * 8));
        }
        #pragma unroll
        for (int i = 0; i < 4; ++i)
            #pragma unroll
            for (int j = 0; j < 4; ++j) {
                acc[i][j] = __builtin_amdgcn_mfma_f32_16x16x32_bf16(af[i][0], bf[j][0], acc[i][j], 0, 0, 0);
                acc[i][j] = __builtin_amdgcn_mfma_f32_16x16x32_bf16(af[i][1], bf[j][1], acc[i][j], 0, 0, 0);
            }
    }

    #pragma unroll
    for (int j = 0; j < 4; ++j) {
        int col = n0 + wn * 64 + j * 16 + cc;
        float bv = f32 ? ((const float*)jb.bias)[col] : bf2f(((const u16*)jb.bias)[col]);
        #pragma unroll
        for (int i = 0; i < 4; ++i)
            #pragma unroll
            for (int r = 0; r < 4; ++r) {
                int row = m0 + wm * 64 + i * 16 + quad * 4 + r;
                float vo = (acc[i][j][r] + bv) * jb.scale;
                if (jb.cmode == 0) {
                    ((u16*)jb.C)[(size_t)row * D_MODEL + col] = f2bf(vo);
                } else if (jb.cmode == 1) {
                    int bb = row >> 11, tok = row & (SEQ - 1);
                    int hh = col >> 6, dd = col & 63;
                    int tile = tok >> 6, n = tok & 63;
                    int kap = ((n & 15) << 2) + (n >> 4);
                    ((u16*)jb.C)[((size_t)((bb * NHEADS + hh) * DEPTH + dd)) * SEQ
                                 + tile * 64 + kap] = f2bf(vo);
                } else {
                    if (f32) ((float*)jb.C)[(size_t)row * D_MODEL + col] = vo;
                    else     ((u16*)jb.C)[(size_t)row * D_MODEL + col] = f2bf(vo);
                }
            }
    }
}

// ---------------------------------------------------------------------------
// Pipelined cooperative flash attention (unchanged from round 6 — validated).
// ---------------------------------------------------------------------------
__global__ __launch_bounds__(256, 3)
void attn3(const u16* __restrict__ Qp, const u16* __restrict__ Kp,
           const u16* __restrict__ VpT, u16* __restrict__ Ao) {
    __shared__ u16 Kls[2][64 * 64];
    __shared__ u16 Vls[2][64 * 64];
    __shared__ u16 Pls[4][32][72];

    const int tid = threadIdx.x;
    const int w = tid >> 6, lane = tid & 63;
    const int cc = lane & 15, quad = lane >> 4;
    const int qt = (int)(gridDim.x - 1 - blockIdx.x);   // descending for balance
    const int h = blockIdx.y, b = blockIdx.z;
    const int qbase = qt * 128 + w * 32;                // wave's first q row

    bf16x8 qf[2][2];
    #pragma unroll
    for (int mi = 0; mi < 2; ++mi) {
        const u16* qr = Qp + (size_t)(b * SEQ + qbase + mi * 16 + cc) * D_MODEL + h * DEPTH;
        qf[mi][0] = *(const bf16x8*)(qr + quad * 8);
        qf[mi][1] = *(const bf16x8*)(qr + 32 + quad * 8);
    }

    const u16* kbase = Kp + (size_t)(b * SEQ) * D_MODEL + h * DEPTH;
    const u16* vbase = VpT + (size_t)((b * NHEADS + h) * DEPTH) * SEQ;

    const int r8 = lane >> 3;
    const int g8 = ((lane & 7) ^ (r8 & 7)) * 8;

    auto stageKV = [&](int buf, int jt) {
        #pragma unroll
        for (int i = 0; i < 2; ++i) {
            int row = w * 16 + i * 8 + r8;   // local row 0..63
            stage16(kbase + (size_t)(jt * 64 + row) * D_MODEL + g8,
                    &Kls[buf][(w * 16 + i * 8) * 64]);
            stage16(vbase + (size_t)row * SEQ + jt * 64 + g8,
                    &Vls[buf][(w * 16 + i * 8) * 64]);
        }
    };

    f32x4 zero4 = {0.f, 0.f, 0.f, 0.f};
    f32x4 oacc[2][4];
    #pragma unroll
    for (int mi = 0; mi < 2; ++mi)
        #pragma unroll
        for (int db = 0; db < 4; ++db) oacc[mi][db] = zero4;
    float m_run[2][4], l_run[2][4];
    #pragma unroll
    for (int mi = 0; mi < 2; ++mi)
        #pragma unroll
        for (int r = 0; r < 4; ++r) { m_run[mi][r] = -1e30f; l_run[mi][r] = 0.f; }

    const int jtmax = 2 * qt + 1;
    stageKV(0, 0);

    for (int jt = 0; jt <= jtmax; ++jt) {
        const int cur = jt & 1;
        __syncthreads();
        if (jt < jtmax) stageKV(cur ^ 1, jt + 1);

        if (jt * 64 > qbase + 31) continue;

        const int sw = cc & 7;
        bf16x8 kf[4][2];
        #pragma unroll
        for (int nb = 0; nb < 4; ++nb) {
            const u16* kr = &Kls[cur][(nb * 16 + cc) * 64];
            kf[nb][0] = *(const bf16x8*)(kr + ((quad ^ sw) * 8));
            kf[nb][1] = *(const bf16x8*)(kr + (((4 + quad) ^ sw) * 8));
        }
        f32x4 s[2][4];
        #pragma unroll
        for (int mi = 0; mi < 2; ++mi)
            #pragma unroll
            for (int nb = 0; nb < 4; ++nb) {
                s[mi][nb] = __builtin_amdgcn_mfma_f32_16x16x32_bf16(qf[mi][0], kf[nb][0], zero4, 0, 0, 0);
                s[mi][nb] = __builtin_amdgcn_mfma_f32_16x16x32_bf16(qf[mi][1], kf[nb][1], s[mi][nb], 0, 0, 0);
            }
        #pragma unroll
        for (int mi = 0; mi < 2; ++mi) {
            if (jt * 64 + 63 > qbase + mi * 16) {
                #pragma unroll
                for (int nb = 0; nb < 4; ++nb)
                    #pragma unroll
                    for (int r = 0; r < 4; ++r)
                        if (jt * 64 + nb * 16 + cc > qbase + mi * 16 + quad * 4 + r)
                            s[mi][nb][r] = -1e30f;
            }
        }

        float alpha[2][4];
        #pragma unroll
        for (int mi = 0; mi < 2; ++mi) {
            #pragma unroll
            for (int r = 0; r < 4; ++r) {
                float mrow = redmax16(fmaxf(fmaxf(s[mi][0][r], s[mi][1][r]),
                                            fmaxf(s[mi][2][r], s[mi][3][r])));
                float mn = fmaxf(m_run[mi][r], mrow);
                alpha[mi][r] = exp2f_hw(m_run[mi][r] - mn);
                m_run[mi][r] = mn;
            }
            #pragma unroll
            for (int nb = 0; nb < 4; ++nb)
                #pragma unroll
                for (int r = 0; r < 4; ++r)
                    s[mi][nb][r] = exp2f_hw(s[mi][nb][r] - m_run[mi][r]);
            #pragma unroll
            for (int r = 0; r < 4; ++r)
                l_run[mi][r] = l_run[mi][r] * alpha[mi][r]
                             + ((s[mi][0][r] + s[mi][1][r]) + (s[mi][2][r] + s[mi][3][r]));
            #pragma unroll
            for (int db = 0; db < 4; ++db)
                #pragma unroll
                for (int r = 0; r < 4; ++r)
                    oacc[mi][db][r] *= alpha[mi][r];
        }

        #pragma unroll
        for (int mi = 0; mi < 2; ++mi)
            #pragma unroll
            for (int r = 0; r < 4; ++r) {
                u32 p01 = __builtin_amdgcn_perm(fbits(s[mi][1][r]), fbits(s[mi][0][r]), 0x07060302u);
                u32 p23 = __builtin_amdgcn_perm(fbits(s[mi][3][r]), fbits(s[mi][2][r]), 0x07060302u);
                uint2 pk; pk.x = p01; pk.y = p23;
                *(uint2*)&Pls[w][mi * 16 + quad * 4 + r][4 * cc] = pk;
            }
        __asm__ volatile("" ::: "memory");

        bf16x8 pf[2][2];
        #pragma unroll
        for (int mi = 0; mi < 2; ++mi) {
            pf[mi][0] = *(const bf16x8*)&Pls[w][mi * 16 + cc][quad * 8];
            pf[mi][1] = *(const bf16x8*)&Pls[w][mi * 16 + cc][32 + quad * 8];
        }
        #pragma unroll
        for (int db = 0; db < 4; ++db) {
            const u16* vr = &Vls[cur][(db * 16 + cc) * 64];
            bf16x8 v0 = *(const bf16x8*)(vr + ((quad ^ sw) * 8));
            bf16x8 v1 = *(const bf16x8*)(vr + (((4 + quad) ^ sw) * 8));
            #pragma unroll
            for (int mi = 0; mi < 2; ++mi) {
                oacc[mi][db] = __builtin_amdgcn_mfma_f32_16x16x32_bf16(pf[mi][0], v0, oacc[mi][db], 0, 0, 0);
                oacc[mi][db] = __builtin_amdgcn_mfma_f32_16x16x32_bf16(pf[mi][1], v1, oacc[mi][db], 0, 0, 0);
            }
        }
    }

    #pragma unroll
    for (int mi = 0; mi < 2; ++mi) {
        float linv[4];
        #pragma unroll
        for (int r = 0; r < 4; ++r) linv[r] = 1.0f / redsum16(l_run[mi][r]);
        #pragma unroll
        for (int db = 0; db < 4; ++db)
            #pragma unroll
            for (int r = 0; r < 4; ++r) {
                size_t row = (size_t)(b * SEQ + qbase + mi * 16 + quad * 4 + r);
                Ao[row * D_MODEL + h * DEPTH + db * 16 + cc] =
                    f2bf(oacc[mi][db][r] * linv[r]);
            }
    }
}

// ---------------------------------------------------------------------------
extern "C" void kernel_launch(void* const* d_in, const int* in_sizes, int n_in,
                              void* d_out, int out_size, void* d_ws, size_t ws_size,
                              hipStream_t stream) {
    const void* v  = d_in[0];
    const void* k  = d_in[1];
    const void* q  = d_in[2];
    // d_in[3] = mask (unused: causal bound applied analytically)
    const void* Wq = d_in[4];
    const void* bq = d_in[5];
    const void* Wk = d_in[6];
    const void* bk = d_in[7];
    const void* Wv = d_in[8];
    const void* bv = d_in[9];
    const void* Wo = d_in[10];
    const void* bo = d_in[11];

    char* base = (char*)d_ws;
    int* flag = (int*)base;
    const size_t WSZ = (size_t)D_MODEL * D_MODEL;   // 1M elems (2MB bf16)
    const size_t TOK = (size_t)M_TOT * D_MODEL;     // 4M elems (8MB bf16)
    u16* WqT = (u16*)(base + 256);
    u16* WkT = WqT + WSZ;
    u16* WvT = WkT + WSZ;
    u16* WoT = WvT + WSZ;
    u16* Qb  = WoT + WSZ;   // converted bf16 q; ALIASED as Ao after QKV gemm
    u16* Kb  = Qb + TOK;
    u16* Vb  = Kb + TOK;
    u16* Qp  = Vb + TOK;
    u16* Kp  = Qp + TOK;
    u16* VpT = Kp + TOK;    // [B][H][DEPTH][SEQ], kappa-permuted per 64-tile
    u16* Ao  = Qb;          // alias: Qb dead after QKV gemm. total ~48.3 MB

    sniff_kernel<<<1, 64, 0, stream>>>((const u16*)q, flag);

    conv_kernel<<<dim3(2048, 1, 3), 256, 0, stream>>>(q, k, v, Qb, Kb, Vb, flag);
    wT_kernel<<<dim3(16, 16, 4), 256, 0, stream>>>(Wq, Wk, Wv, Wo,
                                                   WqT, WkT, WvT, WoT, flag);

    GemmJob jq = {Qb, WqT, bq, Qp,    0, Q_SCALE};
    GemmJob jk = {Kb, WkT, bk, Kp,    0, 1.0f};
    GemmJob jv = {Vb, WvT, bv, VpT,   1, 1.0f};
    gemm6<<<dim3(8, 32, 3), 256, 0, stream>>>(jq, jk, jv, flag);

    attn3<<<dim3(16, 16, 2), 256, 0, stream>>>(Qp, Kp, VpT, Ao);

    GemmJob jo = {Ao, WoT, bo, d_out, 2, 1.0f};
    gemm6<<<dim3(8, 32, 1), 256, 0, stream>>>(jo, jo, jo, flag);
}